// Round 1
// baseline (976.576 us; speedup 1.0000x reference)
//
#include <hip/hip_runtime.h>

#define NB_B 4
#define NB_L 8
#define NB_N 2048
#define NB_C 32
#define NB_M 1024

// workspace layout (float offsets)
#define ANCH_OFF  0          // 32*1024*3 = 98304
#define FT_OFF    98304      // 32*2048*32 = 2097152
#define XRAW_OFF  2195456    // 8*4*1024*192 = 6291456
#define STATS_OFF 8486912    // 2*1536 = 3072

// ---------------------------------------------------------------- transpose
// ft[b][fl][n][c] = features[b][fl][c][n]
__global__ __launch_bounds__(256) void transpose_kernel(const float* __restrict__ f,
                                                        float* __restrict__ ft) {
  __shared__ float tile[NB_C][65];
  int frame = blockIdx.x >> 5;          // b*L+l, 32 frames
  int n0 = (blockIdx.x & 31) * 64;
  int t = threadIdx.x;
  const float* src = f + (size_t)frame * NB_C * NB_N;
#pragma unroll
  for (int i = 0; i < 8; ++i) {
    int q = t + i * 256;
    int c = q >> 6, n = q & 63;
    tile[c][n] = src[c * NB_N + n0 + n];
  }
  __syncthreads();
  float* dst = ft + ((size_t)frame * NB_N + n0) * NB_C;
  int n = t >> 2, c0 = (t & 3) * 8;
  float v[8];
#pragma unroll
  for (int i = 0; i < 8; ++i) v[i] = tile[c0 + i][n];
  float4 w0 = {v[0], v[1], v[2], v[3]};
  float4 w1 = {v[4], v[5], v[6], v[7]};
  *(float4*)(dst + n * NB_C + c0) = w0;
  *(float4*)(dst + n * NB_C + c0 + 4) = w1;
}

// ---------------------------------------------------------------- FPS
__device__ __forceinline__ unsigned long long umax64(unsigned long long a,
                                                     unsigned long long b) {
  return a > b ? a : b;
}

__global__ __launch_bounds__(256) void fps_kernel(const float* __restrict__ xyzs,
                                                  float* __restrict__ anchors,
                                                  float* __restrict__ d_out) {
  int cloud = blockIdx.x;               // b*L + l
  int t = threadIdx.x;
  const float* xyz = xyzs + (size_t)cloud * NB_N * 3;
  __shared__ float pos_lds[NB_N * 3];
  __shared__ unsigned long long red[2][4];
#pragma unroll
  for (int i = 0; i < 24; ++i) {
    int q = t + i * 256;
    pos_lds[q] = xyz[q];
  }
  __syncthreads();
  float px[8], py[8], pz[8], dist[8];
#pragma unroll
  for (int j = 0; j < 8; ++j) {
    int n = j * 256 + t;
    px[j] = pos_lds[n * 3 + 0];
    py[j] = pos_lds[n * 3 + 1];
    pz[j] = pos_lds[n * 3 + 2];
    dist[j] = 3.402823466e38f;
  }
  int last = 0;
  for (int m = 0; m < NB_M; ++m) {
    float lx = pos_lds[last * 3 + 0];
    float ly = pos_lds[last * 3 + 1];
    float lz = pos_lds[last * 3 + 2];
    if (t == 0) {
      size_t o = ((size_t)cloud * NB_M + m) * 3;
      anchors[o + 0] = lx; anchors[o + 1] = ly; anchors[o + 2] = lz;
      d_out[o + 0] = lx;   d_out[o + 1] = ly;   d_out[o + 2] = lz;
    }
    unsigned long long best = 0;
#pragma unroll
    for (int j = 0; j < 8; ++j) {
      // exact reference arithmetic: no FMA contraction, (dx^2+dy^2)+dz^2
      float dx = __fsub_rn(px[j], lx);
      float dy = __fsub_rn(py[j], ly);
      float dz = __fsub_rn(pz[j], lz);
      float d = __fadd_rn(__fadd_rn(__fmul_rn(dx, dx), __fmul_rn(dy, dy)),
                          __fmul_rn(dz, dz));
      float dj = fminf(dist[j], d);
      dist[j] = dj;
      unsigned long long pk =
          ((unsigned long long)__float_as_uint(dj) << 32) |
          (unsigned)(0x7FFFFFFF - (j * 256 + t));
      best = umax64(best, pk);
    }
#pragma unroll
    for (int off = 1; off < 64; off <<= 1)
      best = umax64(best, __shfl_xor(best, off));
    if ((t & 63) == 0) red[m & 1][t >> 6] = best;
    __syncthreads();
    unsigned long long g = red[m & 1][0];
    g = umax64(g, red[m & 1][1]);
    g = umax64(g, red[m & 1][2]);
    g = umax64(g, red[m & 1][3]);
    last = 0x7FFFFFFF - (int)(unsigned)(g & 0xFFFFFFFFull);
  }
}

// ---------------------------------------------------------------- ball query + conv
__device__ __forceinline__ float rdlane(float v, int l) {
  return __int_as_float(__builtin_amdgcn_readlane(__float_as_int(v), l));
}

__global__ __launch_bounds__(256) void bq_conv_kernel(
    const float* __restrict__ xyzs, const float* __restrict__ ft,
    const float* __restrict__ anchors, const float* __restrict__ conv_d_w,
    const float* __restrict__ conv_f_w, float* __restrict__ x_raw) {
  int w = threadIdx.x >> 6, lane = threadIdx.x & 63;
  int task = blockIdx.x * 4 + w;          // cloud*3072 + o*1024 + m
  int cloud = task / 3072;
  int rem = task - cloud * 3072;
  int o = rem >> 10, m = rem & 1023;
  int b = cloud >> 3, l = cloud & 7;
  int nl = l + o - 1;
  float* xout = x_raw + (((size_t)(l * NB_B + b) * NB_M + m) * 192 + o * 64);
  __shared__ int list_s[4][32];
  if (nl < 0 || nl >= NB_L) {             // zero temporal padding frame: exact 0
    xout[lane] = 0.0f;
    return;
  }
  // weights for this lane's output channel
  const float4* wf4 = (const float4*)(conv_f_w + lane * 32);
  float wf[32];
#pragma unroll
  for (int i = 0; i < 8; ++i) {
    float4 v = wf4[i];
    wf[i * 4 + 0] = v.x; wf[i * 4 + 1] = v.y;
    wf[i * 4 + 2] = v.z; wf[i * 4 + 3] = v.w;
  }
  float wd0 = conv_d_w[lane * 3 + 0];
  float wd1 = conv_d_w[lane * 3 + 1];
  float wd2 = conv_d_w[lane * 3 + 2];

  const float* ap = anchors + ((size_t)cloud * NB_M + m) * 3;
  float ax = ap[0], ay = ap[1], az = ap[2];
  const float* nb = xyzs + (size_t)(b * NB_L + nl) * NB_N * 3;

  // ---- ball query: first 32 indices (ascending) with d2 < 0.04
  int count = 0;
  for (int chunk = 0; chunk < 32; ++chunk) {
    int n = chunk * 64 + lane;
    float x = nb[n * 3 + 0], y = nb[n * 3 + 1], z = nb[n * 3 + 2];
    float dx = __fsub_rn(ax, x);
    float dy = __fsub_rn(ay, y);
    float dz = __fsub_rn(az, z);
    float d2 = __fadd_rn(__fadd_rn(__fmul_rn(dx, dx), __fmul_rn(dy, dy)),
                         __fmul_rn(dz, dz));
    bool hit = d2 < 0.04f;
    unsigned long long mask = __ballot(hit);
    int pos = count + __popcll(mask & ((1ull << lane) - 1ull));
    if (hit && pos < 32) list_s[w][pos] = n;
    count += __popcll(mask);
    if (count >= 32) break;
  }
  asm volatile("s_waitcnt lgkmcnt(0)" ::: "memory");
  int cnt = count < 32 ? count : 32;
  int first = (cnt > 0) ? list_s[w][0] : 0;

  // ---- displacement for sample k = lane&31 (lanes 32..63 mirror)
  int k = lane & 31;
  int idxk = (k < cnt) ? list_s[w][k] : first;
  float bx = nb[idxk * 3 + 0], by = nb[idxk * 3 + 1], bz = nb[idxk * 3 + 2];
  float d0 = __fsub_rn(bx, ax);
  float d1 = __fsub_rn(by, ay);
  float d2v = __fsub_rn(bz, az);

  // ---- G = sum_k f_k * disp_k^T  (32c x 3), split k across wave halves
  int c = lane & 31;
  int kbase = (lane >> 5) << 4;
  const float* ftf = ft + (size_t)(b * NB_L + nl) * NB_N * NB_C + c;
  float G0 = 0.f, G1 = 0.f, G2 = 0.f;
#pragma unroll 4
  for (int i = 0; i < 16; ++i) {
    int kk = kbase + i;
    int ik = (kk < cnt) ? list_s[w][kk] : first;
    float fv = ftf[(size_t)ik * NB_C];
    float e0 = __shfl(d0, kk);
    float e1 = __shfl(d1, kk);
    float e2 = __shfl(d2v, kk);
    G0 = fmaf(fv, e0, G0);
    G1 = fmaf(fv, e1, G1);
    G2 = fmaf(fv, e2, G2);
  }
  G0 += __shfl_xor(G0, 32);
  G1 += __shfl_xor(G1, 32);
  G2 += __shfl_xor(G2, 32);

  // ---- out[oc] = sum_c wf[oc,c] * (G[c,:] . wd[oc,:])
  float acc = 0.f;
#pragma unroll
  for (int cc = 0; cc < 32; ++cc) {
    float g0 = rdlane(G0, cc);
    float g1 = rdlane(G1, cc);
    float g2 = rdlane(G2, cc);
    float tt = fmaf(g2, wd2, fmaf(g1, wd1, g0 * wd0));
    acc = fmaf(wf[cc], tt, acc);
  }
  xout[lane] = acc;
}

// ---------------------------------------------------------------- BN stats
__global__ __launch_bounds__(192) void bn_stats_kernel(const float* __restrict__ x_raw,
                                                       float* __restrict__ stats) {
  int bid = blockIdx.x;                  // 8 l * 4 b * 4 mt = 128
  int mt = bid & 3, bb = (bid >> 2) & 3, l = bid >> 4;
  int c = threadIdx.x;                   // 0..191
  const float* p = x_raw + ((size_t)(l * NB_B + bb) * NB_M + mt * 256) * 192 + c;
  float s = 0.f, s2 = 0.f;
  for (int i = 0; i < 256; ++i) {
    float v = p[(size_t)i * 192];
    s += v;
    s2 = fmaf(v, v, s2);
  }
  atomicAdd(&stats[l * 192 + c], s);
  atomicAdd(&stats[1536 + l * 192 + c], s2);
}

// ---------------------------------------------------------------- BN apply + temporal GEMM
__global__ __launch_bounds__(256) void final_kernel(
    const float* __restrict__ x_raw, const float* __restrict__ stats,
    const float* __restrict__ gamma, const float* __restrict__ beta,
    const float* __restrict__ tw, float* __restrict__ out) {
  __shared__ __align__(16) float xn[32 * 192];
  __shared__ __align__(16) float wt[64 * 132];
  __shared__ float sc[192], sh[192];
  int cloud = blockIdx.x >> 5;           // b*L + l
  int mt = blockIdx.x & 31;
  int b = cloud >> 3, l = cloud & 7;
  int m0 = mt * 32;
  int t = threadIdx.x;
  if (t < 192) {
    float mean = stats[l * 192 + t] * (1.0f / 4096.0f);
    float ex2 = stats[1536 + l * 192 + t] * (1.0f / 4096.0f);
    float var = fmaxf(ex2 - mean * mean, 0.0f);
    float g = gamma[t] / sqrtf(var + 1e-5f);
    sc[t] = g;
    sh[t] = fmaf(-mean, g, beta[t]);
  }
  __syncthreads();
  const float* xp = x_raw + ((size_t)(l * NB_B + b) * NB_M + m0) * 192;
#pragma unroll
  for (int i = 0; i < 24; ++i) {
    int q = t + i * 256;
    int cc = q % 192;
    float v = xp[q];
    xn[q] = fmaxf(fmaf(v, sc[cc], sh[cc]), 0.0f);
  }
  float acc[4][4];
#pragma unroll
  for (int i = 0; i < 4; ++i)
#pragma unroll
    for (int j = 0; j < 4; ++j) acc[i][j] = 0.f;
  int o0 = (t & 31) * 4;
  int mg = (t >> 5) * 4;
  for (int kt = 0; kt < 3; ++kt) {
    __syncthreads();
#pragma unroll
    for (int i = 0; i < 32; ++i) {
      int q = t + i * 256;
      int oo = q >> 6, kk = q & 63;
      wt[kk * 132 + oo] = tw[oo * 192 + kt * 64 + kk];
    }
    __syncthreads();
#pragma unroll
    for (int kk = 0; kk < 64; kk += 4) {
      float a[4][4], bb2[4][4];
#pragma unroll
      for (int mi = 0; mi < 4; ++mi) {
        float4 v = *(const float4*)&xn[(mg + mi) * 192 + kt * 64 + kk];
        a[mi][0] = v.x; a[mi][1] = v.y; a[mi][2] = v.z; a[mi][3] = v.w;
      }
#pragma unroll
      for (int j = 0; j < 4; ++j) {
        float4 v = *(const float4*)&wt[(kk + j) * 132 + o0];
        bb2[j][0] = v.x; bb2[j][1] = v.y; bb2[j][2] = v.z; bb2[j][3] = v.w;
      }
#pragma unroll
      for (int mi = 0; mi < 4; ++mi)
#pragma unroll
        for (int j = 0; j < 4; ++j)
#pragma unroll
          for (int oi = 0; oi < 4; ++oi)
            acc[mi][oi] = fmaf(a[mi][j], bb2[j][oi], acc[mi][oi]);
    }
  }
  float* op = out + 98304 + ((size_t)cloud * 128 + o0) * NB_M + m0 + mg;
#pragma unroll
  for (int oi = 0; oi < 4; ++oi) {
    float4 v = {acc[0][oi], acc[1][oi], acc[2][oi], acc[3][oi]};
    *(float4*)(op + (size_t)oi * NB_M) = v;
  }
}

// ---------------------------------------------------------------- launch
extern "C" void kernel_launch(void* const* d_in, const int* in_sizes, int n_in,
                              void* d_out, int out_size, void* d_ws, size_t ws_size,
                              hipStream_t stream) {
  const float* xyzs = (const float*)d_in[0];
  const float* features = (const float*)d_in[1];
  const float* conv_d_w = (const float*)d_in[2];
  const float* conv_f_w = (const float*)d_in[3];
  const float* bn_gamma = (const float*)d_in[4];
  const float* bn_beta = (const float*)d_in[5];
  const float* temporal_w = (const float*)d_in[6];
  float* ws = (float*)d_ws;
  float* anchors = ws + ANCH_OFF;
  float* ft = ws + FT_OFF;
  float* xraw = ws + XRAW_OFF;
  float* stats = ws + STATS_OFF;
  float* out = (float*)d_out;

  hipMemsetAsync(stats, 0, 3072 * sizeof(float), stream);
  transpose_kernel<<<1024, 256, 0, stream>>>(features, ft);
  fps_kernel<<<32, 256, 0, stream>>>(xyzs, anchors, out);
  bq_conv_kernel<<<24576, 256, 0, stream>>>(xyzs, ft, anchors, conv_d_w,
                                            conv_f_w, xraw);
  bn_stats_kernel<<<128, 192, 0, stream>>>(xraw, stats);
  final_kernel<<<1024, 256, 0, stream>>>(xraw, stats, bn_gamma, bn_beta,
                                         temporal_w, out);
}

// Round 2
// 864.714 us; speedup vs baseline: 1.1294x; 1.1294x over previous
//
#include <hip/hip_runtime.h>

#define NB_B 4
#define NB_L 8
#define NB_N 2048
#define NB_C 32
#define NB_M 1024

// workspace layout (float offsets)
#define ANCH_OFF  0          // 32*1024*3 = 98304
#define FT_OFF    98304      // 32*2048*32 = 2097152
#define XRAW_OFF  2195456    // 8*4*1024*192 = 6291456
#define STATS_OFF 8486912    // 2*1536 = 3072

// ---------------------------------------------------------------- transpose
// ft[b][fl][n][c] = features[b][fl][c][n]
__global__ __launch_bounds__(256) void transpose_kernel(const float* __restrict__ f,
                                                        float* __restrict__ ft) {
  __shared__ float tile[NB_C][65];
  int frame = blockIdx.x >> 5;          // b*L+l, 32 frames
  int n0 = (blockIdx.x & 31) * 64;
  int t = threadIdx.x;
  const float* src = f + (size_t)frame * NB_C * NB_N;
#pragma unroll
  for (int i = 0; i < 8; ++i) {
    int q = t + i * 256;
    int c = q >> 6, n = q & 63;
    tile[c][n] = src[c * NB_N + n0 + n];
  }
  __syncthreads();
  float* dst = ft + ((size_t)frame * NB_N + n0) * NB_C;
  int n = t >> 2, c0 = (t & 3) * 8;
  float v[8];
#pragma unroll
  for (int i = 0; i < 8; ++i) v[i] = tile[c0 + i][n];
  float4 w0 = {v[0], v[1], v[2], v[3]};
  float4 w1 = {v[4], v[5], v[6], v[7]};
  *(float4*)(dst + n * NB_C + c0) = w0;
  *(float4*)(dst + n * NB_C + c0 + 4) = w1;
}

// ---------------------------------------------------------------- FPS
__device__ __forceinline__ unsigned long long umax64(unsigned long long a,
                                                     unsigned long long b) {
  return a > b ? a : b;
}

// butterfly-exchange a u64 via DPP (ctrl must be compile-time)
template <int CTRL>
__device__ __forceinline__ unsigned long long dpp_xch64(unsigned long long v) {
  int lo = (int)(unsigned)v;
  int hi = (int)(unsigned)(v >> 32);
  int plo = __builtin_amdgcn_update_dpp(0, lo, CTRL, 0xF, 0xF, false);
  int phi = __builtin_amdgcn_update_dpp(0, hi, CTRL, 0xF, 0xF, false);
  return ((unsigned long long)(unsigned)phi << 32) | (unsigned)plo;
}

__device__ __forceinline__ unsigned long long swz_xor16_64(unsigned long long v) {
  int lo = (int)(unsigned)v;
  int hi = (int)(unsigned)(v >> 32);
  int plo = __builtin_amdgcn_ds_swizzle(lo, 0x401F);  // xor 16 within 32-lane group
  int phi = __builtin_amdgcn_ds_swizzle(hi, 0x401F);
  return ((unsigned long long)(unsigned)phi << 32) | (unsigned)plo;
}

#define DPP_XOR1 0xB1   // quad_perm [1,0,3,2]
#define DPP_XOR2 0x4E   // quad_perm [2,3,0,1]
#define DPP_HMIR 0x141  // row_half_mirror (crosses quads within 8)
#define DPP_MIR  0x140  // row_mirror (crosses 8-halves within 16)

#define FPS_T 512

__global__ __launch_bounds__(FPS_T) void fps_kernel(const float* __restrict__ xyzs,
                                                    float* __restrict__ anchors,
                                                    float* __restrict__ d_out) {
  int cloud = blockIdx.x;               // b*L + l
  int t = threadIdx.x;
  int lane = t & 63;
  const float* xyz = xyzs + (size_t)cloud * NB_N * 3;
  __shared__ float4 pos4[NB_N];                 // 32 KB
  __shared__ unsigned long long red[2][8];
  __shared__ int hist[NB_M];                    // 4 KB
  for (int i = t; i < NB_N; i += FPS_T) {
    float x = xyz[i * 3 + 0];
    float y = xyz[i * 3 + 1];
    float z = xyz[i * 3 + 2];
    pos4[i] = make_float4(x, y, z, 0.f);
  }
  __syncthreads();
  float px[4], py[4], pz[4], dist[4];
  unsigned inv[4];
#pragma unroll
  for (int j = 0; j < 4; ++j) {
    int n = j * FPS_T + t;
    float4 p = pos4[n];
    px[j] = p.x; py[j] = p.y; pz[j] = p.z;
    dist[j] = 3.402823466e38f;
    inv[j] = 0x7FFFFFFFu - (unsigned)n;
  }
  int last = 0;
  float4 sp = pos4[0];
  float lx = sp.x, ly = sp.y, lz = sp.z;
  for (int m = 0; m < NB_M; ++m) {
    if (t == 0) hist[m] = last;       // reference emits the incoming seed at step m
    unsigned long long best = 0;
#pragma unroll
    for (int j = 0; j < 4; ++j) {
      // exact reference arithmetic: no FMA contraction, (dx^2+dy^2)+dz^2
      float dx = __fsub_rn(px[j], lx);
      float dy = __fsub_rn(py[j], ly);
      float dz = __fsub_rn(pz[j], lz);
      float d = __fadd_rn(__fadd_rn(__fmul_rn(dx, dx), __fmul_rn(dy, dy)),
                          __fmul_rn(dz, dz));
      float dj = fminf(dist[j], d);
      dist[j] = dj;
      unsigned long long pk =
          ((unsigned long long)__float_as_uint(dj) << 32) | inv[j];
      best = umax64(best, pk);
    }
    // intra-wave all-reduce (max), DPP butterfly + swizzle + cross-32 shuffle
    best = umax64(best, dpp_xch64<DPP_XOR1>(best));
    best = umax64(best, dpp_xch64<DPP_XOR2>(best));
    best = umax64(best, dpp_xch64<DPP_HMIR>(best));
    best = umax64(best, dpp_xch64<DPP_MIR>(best));
    best = umax64(best, swz_xor16_64(best));
    best = umax64(best, __shfl_xor(best, 32));
    if (lane == 0) red[m & 1][t >> 6] = best;
    __syncthreads();
    // cross-wave combine: lane l holds slot l&7; 3-step DPP butterfly all-reduces
    unsigned long long g = red[m & 1][lane & 7];
    g = umax64(g, dpp_xch64<DPP_XOR1>(g));
    g = umax64(g, dpp_xch64<DPP_XOR2>(g));
    g = umax64(g, dpp_xch64<DPP_HMIR>(g));
    last = 0x7FFFFFFF - (int)(unsigned)g;
    float4 p = pos4[last];
    lx = p.x; ly = p.y; lz = p.z;
  }
  __syncthreads();
  for (int mm = t; mm < NB_M; mm += FPS_T) {
    int idx = hist[mm];
    float4 p = pos4[idx];
    size_t o = ((size_t)cloud * NB_M + mm) * 3;
    anchors[o + 0] = p.x; anchors[o + 1] = p.y; anchors[o + 2] = p.z;
    d_out[o + 0] = p.x;   d_out[o + 1] = p.y;   d_out[o + 2] = p.z;
  }
}

// ---------------------------------------------------------------- ball query + conv
__device__ __forceinline__ float rdlane(float v, int l) {
  return __int_as_float(__builtin_amdgcn_readlane(__float_as_int(v), l));
}

__global__ __launch_bounds__(256) void bq_conv_kernel(
    const float* __restrict__ xyzs, const float* __restrict__ ft,
    const float* __restrict__ anchors, const float* __restrict__ conv_d_w,
    const float* __restrict__ conv_f_w, float* __restrict__ x_raw) {
  int w = threadIdx.x >> 6, lane = threadIdx.x & 63;
  int task = blockIdx.x * 4 + w;          // cloud*3072 + o*1024 + m
  int cloud = task / 3072;
  int rem = task - cloud * 3072;
  int o = rem >> 10, m = rem & 1023;
  int b = cloud >> 3, l = cloud & 7;
  int nl = l + o - 1;
  float* xout = x_raw + (((size_t)(l * NB_B + b) * NB_M + m) * 192 + o * 64);
  __shared__ int list_s[4][32];
  if (nl < 0 || nl >= NB_L) {             // zero temporal padding frame: exact 0
    xout[lane] = 0.0f;
    return;
  }
  // weights for this lane's output channel
  const float4* wf4 = (const float4*)(conv_f_w + lane * 32);
  float wf[32];
#pragma unroll
  for (int i = 0; i < 8; ++i) {
    float4 v = wf4[i];
    wf[i * 4 + 0] = v.x; wf[i * 4 + 1] = v.y;
    wf[i * 4 + 2] = v.z; wf[i * 4 + 3] = v.w;
  }
  float wd0 = conv_d_w[lane * 3 + 0];
  float wd1 = conv_d_w[lane * 3 + 1];
  float wd2 = conv_d_w[lane * 3 + 2];

  const float* ap = anchors + ((size_t)cloud * NB_M + m) * 3;
  float ax = ap[0], ay = ap[1], az = ap[2];
  const float* nb = xyzs + (size_t)(b * NB_L + nl) * NB_N * 3;

  // ---- ball query: first 32 indices (ascending) with d2 < 0.04
  // 2 chunks (128 points) per loop iteration to halve the serial
  // load->ballot->break chain
  unsigned long long lmlt = (1ull << lane) - 1ull;
  int count = 0;
  for (int it = 0; it < 16; ++it) {
    int n0 = it * 128 + lane;
    int n1 = n0 + 64;
    float x0 = nb[n0 * 3 + 0], y0 = nb[n0 * 3 + 1], z0 = nb[n0 * 3 + 2];
    float x1 = nb[n1 * 3 + 0], y1 = nb[n1 * 3 + 1], z1 = nb[n1 * 3 + 2];
    float dx0 = __fsub_rn(ax, x0), dy0 = __fsub_rn(ay, y0), dz0 = __fsub_rn(az, z0);
    float d20 = __fadd_rn(__fadd_rn(__fmul_rn(dx0, dx0), __fmul_rn(dy0, dy0)),
                          __fmul_rn(dz0, dz0));
    float dx1 = __fsub_rn(ax, x1), dy1 = __fsub_rn(ay, y1), dz1 = __fsub_rn(az, z1);
    float d21 = __fadd_rn(__fadd_rn(__fmul_rn(dx1, dx1), __fmul_rn(dy1, dy1)),
                          __fmul_rn(dz1, dz1));
    bool h0 = d20 < 0.04f;
    bool h1 = d21 < 0.04f;
    unsigned long long m0 = __ballot(h0);
    int p0 = count + __popcll(m0 & lmlt);
    if (h0 && p0 < 32) list_s[w][p0] = n0;
    int c0 = count + __popcll(m0);
    unsigned long long m1 = __ballot(h1);
    int p1 = c0 + __popcll(m1 & lmlt);
    if (h1 && p1 < 32) list_s[w][p1] = n1;
    count = c0 + __popcll(m1);
    if (count >= 32) break;
  }
  asm volatile("s_waitcnt lgkmcnt(0)" ::: "memory");
  int cnt = count < 32 ? count : 32;
  int first = (cnt > 0) ? list_s[w][0] : 0;

  // ---- displacement for sample k = lane&31 (lanes 32..63 mirror)
  int k = lane & 31;
  int idxk = (k < cnt) ? list_s[w][k] : first;
  float bx = nb[idxk * 3 + 0], by = nb[idxk * 3 + 1], bz = nb[idxk * 3 + 2];
  float d0 = __fsub_rn(bx, ax);
  float d1 = __fsub_rn(by, ay);
  float d2v = __fsub_rn(bz, az);

  // ---- G = sum_k f_k * disp_k^T  (32c x 3), split k across wave halves
  int c = lane & 31;
  int kbase = (lane >> 5) << 4;
  const float* ftf = ft + (size_t)(b * NB_L + nl) * NB_N * NB_C + c;
  float G0 = 0.f, G1 = 0.f, G2 = 0.f;
#pragma unroll 4
  for (int i = 0; i < 16; ++i) {
    int kk = kbase + i;
    int ik = (kk < cnt) ? list_s[w][kk] : first;
    float fv = ftf[(size_t)ik * NB_C];
    float e0 = __shfl(d0, kk);
    float e1 = __shfl(d1, kk);
    float e2 = __shfl(d2v, kk);
    G0 = fmaf(fv, e0, G0);
    G1 = fmaf(fv, e1, G1);
    G2 = fmaf(fv, e2, G2);
  }
  G0 += __shfl_xor(G0, 32);
  G1 += __shfl_xor(G1, 32);
  G2 += __shfl_xor(G2, 32);

  // ---- out[oc] = sum_c wf[oc,c] * (G[c,:] . wd[oc,:])
  float acc = 0.f;
#pragma unroll
  for (int cc = 0; cc < 32; ++cc) {
    float g0 = rdlane(G0, cc);
    float g1 = rdlane(G1, cc);
    float g2 = rdlane(G2, cc);
    float tt = fmaf(g2, wd2, fmaf(g1, wd1, g0 * wd0));
    acc = fmaf(wf[cc], tt, acc);
  }
  xout[lane] = acc;
}

// ---------------------------------------------------------------- BN stats
__global__ __launch_bounds__(192) void bn_stats_kernel(const float* __restrict__ x_raw,
                                                       float* __restrict__ stats) {
  int bid = blockIdx.x;                  // 8 l * 4 b * 4 mt = 128
  int mt = bid & 3, bb = (bid >> 2) & 3, l = bid >> 4;
  int c = threadIdx.x;                   // 0..191
  const float* p = x_raw + ((size_t)(l * NB_B + bb) * NB_M + mt * 256) * 192 + c;
  float s = 0.f, s2 = 0.f;
  for (int i = 0; i < 256; ++i) {
    float v = p[(size_t)i * 192];
    s += v;
    s2 = fmaf(v, v, s2);
  }
  atomicAdd(&stats[l * 192 + c], s);
  atomicAdd(&stats[1536 + l * 192 + c], s2);
}

// ---------------------------------------------------------------- BN apply + temporal GEMM
__global__ __launch_bounds__(256) void final_kernel(
    const float* __restrict__ x_raw, const float* __restrict__ stats,
    const float* __restrict__ gamma, const float* __restrict__ beta,
    const float* __restrict__ tw, float* __restrict__ out) {
  __shared__ __align__(16) float xn[32 * 192];
  __shared__ __align__(16) float wt[64 * 132];
  __shared__ float sc[192], sh[192];
  int cloud = blockIdx.x >> 5;           // b*L + l
  int mt = blockIdx.x & 31;
  int b = cloud >> 3, l = cloud & 7;
  int m0 = mt * 32;
  int t = threadIdx.x;
  if (t < 192) {
    float mean = stats[l * 192 + t] * (1.0f / 4096.0f);
    float ex2 = stats[1536 + l * 192 + t] * (1.0f / 4096.0f);
    float var = fmaxf(ex2 - mean * mean, 0.0f);
    float g = gamma[t] / sqrtf(var + 1e-5f);
    sc[t] = g;
    sh[t] = fmaf(-mean, g, beta[t]);
  }
  __syncthreads();
  const float* xp = x_raw + ((size_t)(l * NB_B + b) * NB_M + m0) * 192;
#pragma unroll
  for (int i = 0; i < 24; ++i) {
    int q = t + i * 256;
    int cc = q % 192;
    float v = xp[q];
    xn[q] = fmaxf(fmaf(v, sc[cc], sh[cc]), 0.0f);
  }
  float acc[4][4];
#pragma unroll
  for (int i = 0; i < 4; ++i)
#pragma unroll
    for (int j = 0; j < 4; ++j) acc[i][j] = 0.f;
  int o0 = (t & 31) * 4;
  int mg = (t >> 5) * 4;
  for (int kt = 0; kt < 3; ++kt) {
    __syncthreads();
#pragma unroll
    for (int i = 0; i < 32; ++i) {
      int q = t + i * 256;
      int oo = q >> 6, kk = q & 63;
      wt[kk * 132 + oo] = tw[oo * 192 + kt * 64 + kk];
    }
    __syncthreads();
#pragma unroll
    for (int kk = 0; kk < 64; kk += 4) {
      float a[4][4], bb2[4][4];
#pragma unroll
      for (int mi = 0; mi < 4; ++mi) {
        float4 v = *(const float4*)&xn[(mg + mi) * 192 + kt * 64 + kk];
        a[mi][0] = v.x; a[mi][1] = v.y; a[mi][2] = v.z; a[mi][3] = v.w;
      }
#pragma unroll
      for (int j = 0; j < 4; ++j) {
        float4 v = *(const float4*)&wt[(kk + j) * 132 + o0];
        bb2[j][0] = v.x; bb2[j][1] = v.y; bb2[j][2] = v.z; bb2[j][3] = v.w;
      }
#pragma unroll
      for (int mi = 0; mi < 4; ++mi)
#pragma unroll
        for (int j = 0; j < 4; ++j)
#pragma unroll
          for (int oi = 0; oi < 4; ++oi)
            acc[mi][oi] = fmaf(a[mi][j], bb2[j][oi], acc[mi][oi]);
    }
  }
  float* op = out + 98304 + ((size_t)cloud * 128 + o0) * NB_M + m0 + mg;
#pragma unroll
  for (int oi = 0; oi < 4; ++oi) {
    float4 v = {acc[0][oi], acc[1][oi], acc[2][oi], acc[3][oi]};
    *(float4*)(op + (size_t)oi * NB_M) = v;
  }
}

// ---------------------------------------------------------------- launch
extern "C" void kernel_launch(void* const* d_in, const int* in_sizes, int n_in,
                              void* d_out, int out_size, void* d_ws, size_t ws_size,
                              hipStream_t stream) {
  const float* xyzs = (const float*)d_in[0];
  const float* features = (const float*)d_in[1];
  const float* conv_d_w = (const float*)d_in[2];
  const float* conv_f_w = (const float*)d_in[3];
  const float* bn_gamma = (const float*)d_in[4];
  const float* bn_beta = (const float*)d_in[5];
  const float* temporal_w = (const float*)d_in[6];
  float* ws = (float*)d_ws;
  float* anchors = ws + ANCH_OFF;
  float* ft = ws + FT_OFF;
  float* xraw = ws + XRAW_OFF;
  float* stats = ws + STATS_OFF;
  float* out = (float*)d_out;

  hipMemsetAsync(stats, 0, 3072 * sizeof(float), stream);
  transpose_kernel<<<1024, 256, 0, stream>>>(features, ft);
  fps_kernel<<<32, FPS_T, 0, stream>>>(xyzs, anchors, out);
  bq_conv_kernel<<<24576, 256, 0, stream>>>(xyzs, ft, anchors, conv_d_w,
                                            conv_f_w, xraw);
  bn_stats_kernel<<<128, 192, 0, stream>>>(xraw, stats);
  final_kernel<<<1024, 256, 0, stream>>>(xraw, stats, bn_gamma, bn_beta,
                                         temporal_w, out);
}